// Round 6
// baseline (4928.603 us; speedup 1.0000x reference)
//
#include <hip/hip_runtime.h>
#include <cstdint>
#include <cstddef>

#define B_    256
#define T_    1024
#define NDYN  20
#define DH    64
#define DZ    128
#define HIDN  64
#define GCOLS 384   // 3*DZ
#define XDIM  104   // 2*NDYN + DH
#define THR   512   // 8 waves: every RK4 phase uses all lanes

// Whh split: rows 0..67 in LDS (float4-interleaved), rows 68..127 in registers
// as TWO arrays of <=32 floats (SROA promotes <=32-elem arrays reliably).
#define WHH_LDS_G 17          // 17 groups of 4 rows = rows 0..67
#define WHH_REGA  32          // rows 68..99
#define WHH_REGB  28          // rows 100..127

// chunk-padded LDS index: 16-float chunks at stride 20 (conflict-free float4 reads)
__device__ __forceinline__ int cpad(int k) { return (k >> 4) * 20 + (k & 15); }

// Raw block barrier: LDS ordering only (lgkmcnt), NO vmcnt drain.
// __syncthreads() emits s_waitcnt vmcnt(0) before s_barrier, which pulls the
// gi_pre global load (~400-900 cy) and Z-store acks into the serial phase
// chain every step. With lgkm-only, the gi load issued at step start has ~12
// barriers to land; the compiler still emits its own vmcnt wait at the USE.
#define BAR() do { asm volatile("s_waitcnt lgkmcnt(0)" ::: "memory"); \
                   __builtin_amdgcn_s_barrier(); } while (0)

// DPP cross-lane ops (VALU pipe, not LDS).
// dpp_sum CTRLs: 0xB1=quad_perm(1,0,3,2)~xor1, 0x4E=quad_perm(2,3,0,1)~xor2,
// 0x141=row_half_mirror~xor4. dpp_mov CTRLs: 0x55=quad_perm(1,1,1,1) [bcast
// lane1 of quad], 0xAA=quad_perm(2,2,2,2) [bcast lane2 of quad].
template<int CTRL, int XORMASK>
__device__ __forceinline__ float dpp_sum(float v) {
#if __has_builtin(__builtin_amdgcn_mov_dpp)
  int o = __builtin_amdgcn_mov_dpp(__float_as_int(v), CTRL, 0xF, 0xF, true);
  return v + __int_as_float(o);
#else
  return v + __shfl_xor(v, XORMASK);
#endif
}
template<int CTRL, int SRCLANE>
__device__ __forceinline__ float dpp_mov(float v) {
#if __has_builtin(__builtin_amdgcn_mov_dpp)
  return __int_as_float(__builtin_amdgcn_mov_dpp(__float_as_int(v), CTRL, 0xF, 0xF, true));
#else
  return __shfl(v, (threadIdx.x & ~3) + SRCLANE, 64);
#endif
}

__device__ __forceinline__ float tanh_fast(float x) {
  float a = __expf(-2.f * fabsf(x));
  return copysignf((1.f - a) / (1.f + a), x);
}
__device__ __forceinline__ float sigm(float x) { return 1.f / (1.f + __expf(-x)); }

// Register-budget history: backend pins this kernel at 128 arch VGPRs; R5's
// counters show we sit exactly at the spill edge (WRITE_SIZE +36MB marginal
// scratch). Persistent per-thread: w0r(16)+w1r(8)+w2r(16)+whhA(32)+whhB(28)
// = 100 floats. Do NOT add persistent state.
//
// GRU quad mapping (this round): output j = tid>>2; lane tid&3 = gate
// {0=r,1=u,2=n, 3=idle-dup}. The 3 gate sums for output j land in one quad ->
// gate finish via 3 quad_perm DPP moves, NO gateL/gateN LDS and NO barrier
// between GRU matvec and gate finish (14 -> 13 phases/step).
__global__ __launch_bounds__(THR, 1) void odernn_kernel(
    const float* __restrict__ z0, const float* __restrict__ tdyn,
    const float* __restrict__ Y, const float* __restrict__ Mm,
    const float* __restrict__ Hh, const int* __restrict__ lens,
    const float* __restrict__ W0, const float* __restrict__ b0,
    const float* __restrict__ W1, const float* __restrict__ b1,
    const float* __restrict__ W2, const float* __restrict__ b2,
    const float* __restrict__ Wih, const float* __restrict__ bih,
    const float* __restrict__ Whh, const float* __restrict__ bhh,
    const float* __restrict__ gi_pre, float* __restrict__ out, int use_gi)
{
  const int tid = threadIdx.x;
  const int b   = blockIdx.x;

  __shared__ __align__(16) float vinP[160];   // RK4 input v, 8 chunks of 16 @ stride 20
  __shared__ __align__(16) float h1P[80];     // 4 chunks
  __shared__ __align__(16) float h2P[80];     // 4 chunks
  __shared__ __align__(16) float zodeL[128];  // flat, float4-broadcast in GRU
  __shared__ float zcurL[128];
  __shared__ float xsL[112];
  __shared__ float dtL[T_];                   // per-step dt, precomputed at init (4KB)
  // Whh rows 0..67, float4-interleaved, TRIPLE-INTERLEAVED columns:
  // WhhP4[g*384 + 3*j+gate] = {Whh[4g..4g+3][gate*128+j]}. A wave's 64 lanes
  // read 48 consecutive phys slots (+16 dups) -> b128 conflict-free.
  __shared__ __align__(16) float4 WhhP4[WHH_LDS_G * 384];   // 104.4 KB

  // Roles:
  //   L0: out jg0 = tid>>3 (0..63),  K-chunk 16*p0, p0 = tid&7  -> w0r[16]
  //   L1: out jg0,                   K-chunk  8*p0              -> w1r[8]
  //   L2: out j2  = tid>>2 (0..127), K-chunk 16*p2, p2 = tid&3  -> w2r[16]
  //   GRU: out j2, gate cg = min(tid&3,2), column gcol = cg*128 + j2
  const int jg0 = tid >> 3, p0 = tid & 7;
  const int j2  = tid >> 2, p2 = tid & 3;
  const int cg  = (p2 < 3) ? p2 : 2;          // gate==3 lanes dup gate n
  const int gcol = cg * 128 + j2;             // GRU column for this lane
  const int physc = 3 * j2 + cg;              // WhhP4 physical column

  float w0r[16], w1r[8], w2r[16], whhA[WHH_REGA], whhB[WHH_REGB];

  // ---- one-time staging of Whh rows 0..67 into LDS (triple-interleaved) ----
  if (p2 < 3) {
    #pragma unroll 1
    for (int g = 0; g < WHH_LDS_G; ++g) {
      float4 w;
      w.x = Whh[(4 * g + 0) * GCOLS + gcol];
      w.y = Whh[(4 * g + 1) * GCOLS + gcol];
      w.z = Whh[(4 * g + 2) * GCOLS + gcol];
      w.w = Whh[(4 * g + 3) * GCOLS + gcol];
      WhhP4[g * 384 + physc] = w;
    }
  }
  #pragma unroll
  for (int i = 0; i < WHH_REGA; ++i)
    whhA[i] = Whh[(4 * WHH_LDS_G + i) * GCOLS + gcol];            // rows 68..99
  #pragma unroll
  for (int i = 0; i < WHH_REGB; ++i)
    whhB[i] = Whh[(4 * WHH_LDS_G + WHH_REGA + i) * GCOLS + gcol]; // rows 100..127

  #pragma unroll
  for (int i = 0; i < 16; ++i) w0r[i] = W0[(16 * p0 + i) * HIDN + jg0];
  #pragma unroll
  for (int i = 0; i < 8; ++i)  w1r[i] = W1[(8 * p0 + i) * HIDN + jg0];
  #pragma unroll
  for (int i = 0; i < 16; ++i) w2r[i] = W2[(16 * p2 + i) * DZ + j2];

  const float* tdb = tdyn + (size_t)b * T_;
  // dt table: dtL[t] = max(t_dyn[t]-t_dyn[t-1], 0), dtL[0] = 0 (matches
  // reference's t_prev init = t_dyn[:,0]). Removes per-step global loads.
  for (int k = tid; k < T_; k += THR) {
    float tk = tdb[k];
    float tp = (k == 0) ? tk : tdb[k - 1];
    dtL[k] = fmaxf(tk - tp, 0.f);
  }

  float b0r = 0.f, b1r = 0.f, b2r = 0.f;
  if (p0 == 0) { b0r = b0[jg0]; b1r = b1[jg0]; }
  if (p2 == 0) b2r = b2[j2];
  const float bhhr = bhh[gcol];
  const float bihr = bih[gcol];
  const int   lenb = lens[b];

  if (tid < 128) {
    float zv = z0[(size_t)b * DZ + tid];
    vinP[cpad(tid)] = zv;
    zcurL[tid] = zv;
  }
  __syncthreads();   // full barrier once, before the loop

  float* Zbase = out + (size_t)B_ * DZ;

  #pragma unroll 1
  for (int t = 0; t < T_; ++t) {
    const size_t bt = (size_t)b * T_ + t;
    const float dt = dtL[t];   // LDS broadcast; covered by first phases

    float gival = 0.f;
    if (use_gi) {
      // per-lane column gcol; a wave touches 3 (+1 dup) 64B lines -> coalesced
      gival = gi_pre[bt * GCOLS + gcol];   // lands ~12 barriers later
    } else if (tid < XDIM) {
      float v;
      if (tid < 20)      v = Y[bt * NDYN + tid];
      else if (tid < 40) v = Mm[bt * NDYN + (tid - 20)];
      else               v = Hh[bt * DH + (tid - 40)];
      xsL[tid] = v;
    }

    float zreg = 0.f, kacc = 0.f, zode_reg = 0.f;
    if (p2 == 0) zreg = zcurL[j2];

    // rolled: 4 RK stages are barrier-serialized anyway; rolling shrinks live
    // ranges / scheduling windows -> keeps peak VGPR pressure moderate.
    #pragma unroll 1
    for (int e = 0; e < 4; ++e) {
      // ---- L0: 64 outs, K=128; 8 threads/out, K-chunk 16 (all 512 lanes) ----
      // read &vinP[p0*20]: word banks tile 0..31 exactly once -> conflict-free
      {
        const float4* vp = (const float4*)&vinP[p0 * 20];
        float a00 = 0.f, a01 = 0.f;   // split chain: 16-deep -> 2x8
        {
          float4 v0 = vp[0], v1 = vp[1];
          a00 += w0r[0]*v0.x + w0r[1]*v0.y + w0r[2]*v0.z + w0r[3]*v0.w;
          a01 += w0r[4]*v1.x + w0r[5]*v1.y + w0r[6]*v1.z + w0r[7]*v1.w;
        }
        {
          float4 v2 = vp[2], v3 = vp[3];
          a00 += w0r[8]*v2.x + w0r[9]*v2.y + w0r[10]*v2.z + w0r[11]*v2.w;
          a01 += w0r[12]*v3.x + w0r[13]*v3.y + w0r[14]*v3.z + w0r[15]*v3.w;
        }
        float a0 = a00 + a01;
        a0 = dpp_sum<0xB1,1>(a0); a0 = dpp_sum<0x4E,2>(a0); a0 = dpp_sum<0x141,4>(a0);
        if (p0 == 0)
          h1P[cpad(jg0)] = tanh_fast(a0 + b0r);
      }
      BAR();
      // ---- L1: 64 outs, K=64; 8 threads/out, K-chunk 8 (all 512 lanes) ----
      // h1[8p0..8p0+7] is contiguous in the padded layout (8p0 mod 16 in {0,8})
      {
        const float4* hp = (const float4*)&h1P[cpad(8 * p0)];
        float4 v0 = hp[0], v1 = hp[1];
        float a00 = w1r[0]*v0.x + w1r[1]*v0.y + w1r[2]*v0.z + w1r[3]*v0.w;
        float a01 = w1r[4]*v1.x + w1r[5]*v1.y + w1r[6]*v1.z + w1r[7]*v1.w;
        float a0 = a00 + a01;
        a0 = dpp_sum<0xB1,1>(a0); a0 = dpp_sum<0x4E,2>(a0); a0 = dpp_sum<0x141,4>(a0);
        if (p0 == 0)
          h2P[cpad(jg0)] = tanh_fast(a0 + b1r);
      }
      BAR();
      // ---- L2: 128 outs, K=64; 4 threads/out, K-chunk 16 (all 512 lanes) ----
      {
        const float4* hp = (const float4*)&h2P[p2 * 20];
        float a00 = 0.f, a01 = 0.f;
        {
          float4 v0 = hp[0], v1 = hp[1];
          a00 += w2r[0]*v0.x + w2r[1]*v0.y + w2r[2]*v0.z + w2r[3]*v0.w;
          a01 += w2r[4]*v1.x + w2r[5]*v1.y + w2r[6]*v1.z + w2r[7]*v1.w;
        }
        {
          float4 v2 = hp[2], v3 = hp[3];
          a00 += w2r[8]*v2.x + w2r[9]*v2.y + w2r[10]*v2.z + w2r[11]*v2.w;
          a01 += w2r[12]*v3.x + w2r[13]*v3.y + w2r[14]*v3.z + w2r[15]*v3.w;
        }
        float a0 = a00 + a01;
        a0 = dpp_sum<0xB1,1>(a0); a0 = dpp_sum<0x4E,2>(a0);
        if (p2 == 0) {
          const float kv = dt * (a0 + b2r);
          if (e == 0)      kacc = kv;
          else if (e == 3) kacc += kv;
          else             kacc += 2.f * kv;
          if (e < 3) {
            const float a = (e == 2) ? 1.f : 0.5f;
            vinP[cpad(j2)] = zreg + a * kv;
          } else {
            zode_reg = zreg + kacc * (1.f / 6.f);
            zodeL[j2] = zode_reg;   // broadcast source for GRU matvec
          }
        }
      }
      BAR();
    }

    // ---- merged GRU matvec + gate finish (ONE phase, no gateL round-trip).
    // Lane (j2, cg) computes column gcol = cg*128+j2: Whh rows 0..67 from LDS
    // (triple-interleaved, 2-deep pipeline), rows 68..127 from registers.
    // Then 3 quad_perm DPPs gather u/n parts onto lane0 of the quad. ----
    {
      float gh0 = bhhr, gh1 = 0.f, gh2 = 0.f, gh3 = 0.f;
      const float4* zq = (const float4*)zodeL;
      #pragma unroll 1
      for (int g = 0; g < WHH_LDS_G - 1; g += 2) {
        float4 w0 = WhhP4[g * 384 + physc];
        float4 w1 = WhhP4[(g + 1) * 384 + physc];
        float4 za = zq[g];
        float4 zb = zq[g + 1];
        gh0 += w0.x*za.x + w0.y*za.y + w0.z*za.z + w0.w*za.w;
        gh1 += w1.x*zb.x + w1.y*zb.y + w1.z*zb.z + w1.w*zb.w;
      }
      {  // tail group g = 16
        float4 w0 = WhhP4[(WHH_LDS_G - 1) * 384 + physc];
        float4 za = zq[WHH_LDS_G - 1];
        gh0 += w0.x*za.x + w0.y*za.y + w0.z*za.z + w0.w*za.w;
      }
      #pragma unroll   // rows 68..99 (whhA) — compile-time indices
      for (int q = 0; q < 8; ++q) {
        float4 z = zq[WHH_LDS_G + q];
        gh2 += whhA[4*q+0]*z.x + whhA[4*q+1]*z.y + whhA[4*q+2]*z.z + whhA[4*q+3]*z.w;
      }
      #pragma unroll   // rows 100..127 (whhB)
      for (int q = 0; q < 7; ++q) {
        float4 z = zq[WHH_LDS_G + 8 + q];
        gh3 += whhB[4*q+0]*z.x + whhB[4*q+1]*z.y + whhB[4*q+2]*z.z + whhB[4*q+3]*z.w;
      }
      float gh = (gh0 + gh1) + (gh2 + gh3);
      float gi;
      if (use_gi) gi = gival;
      else {
        gi = bihr;
        for (int i = 0; i < XDIM; ++i) gi += xsL[i] * Wih[(size_t)i * GCOLS + gcol];
      }
      // smain: lane0 = r-sum, lane1 = u-sum, lane2 = gh_n (gi_n kept separate
      // because n = tanh(gi_n + r*gh_n)); saux lane2 = gi_n.
      const float smain = (cg == 2) ? gh : (gh + gi);
      const float saux  = gi;
      const float u_s = dpp_mov<0x55, 1>(smain);   // lane1 -> all of quad
      const float ghn = dpp_mov<0xAA, 2>(smain);   // lane2 -> all of quad
      const float gin = dpp_mov<0xAA, 2>(saux);
      if (p2 == 0) {
        const float r  = sigm(smain);
        const float uu = sigm(u_s);
        const float n  = tanh_fast(gin + r * ghn);
        const float zo = zode_reg;                 // kept in-register from e==3
        const float zn = (1.f - uu) * n + uu * zo;
        const float znew = (t < lenb) ? zn : zo;
        vinP[cpad(j2)] = znew;
        zcurL[j2] = znew;
        Zbase[bt * DZ + j2] = znew;
      }
    }
    BAR();
  }

  __syncthreads();
  if (tid < 128) out[(size_t)b * DZ + tid] = zcurL[tid];
}

// ---- pass 1: gi[bt][c] = b_ih[c] + x[bt] @ W_ih  (input-only, fully parallel, fp32)
__global__ __launch_bounds__(384) void gi_precompute(
    const float* __restrict__ Y, const float* __restrict__ Mm,
    const float* __restrict__ Hh, const float* __restrict__ Wih,
    const float* __restrict__ bih, float* __restrict__ gi)
{
  __shared__ float Xs[XDIM][16];
  const int tid = threadIdx.x;
  const size_t bt0 = (size_t)blockIdx.x * 16;
  for (int idx = tid; idx < XDIM * 16; idx += 384) {
    int r = idx & 15, c = idx >> 4;
    size_t bt = bt0 + r;
    float v;
    if (c < 20)      v = Y[bt * NDYN + c];
    else if (c < 40) v = Mm[bt * NDYN + (c - 20)];
    else             v = Hh[bt * DH + (c - 40)];
    Xs[c][r] = v;
  }
  __syncthreads();
  float acc[16];
  const float bv = bih[tid];
  #pragma unroll
  for (int r = 0; r < 16; ++r) acc[r] = bv;
  for (int i = 0; i < XDIM; ++i) {
    float w = Wih[i * GCOLS + tid];
    const float4* xp = (const float4*)(&Xs[i][0]);
    #pragma unroll
    for (int q = 0; q < 4; ++q) {
      float4 xv = xp[q];
      acc[4*q + 0] += xv.x * w;
      acc[4*q + 1] += xv.y * w;
      acc[4*q + 2] += xv.z * w;
      acc[4*q + 3] += xv.w * w;
    }
  }
  #pragma unroll
  for (int r = 0; r < 16; ++r) gi[(bt0 + r) * GCOLS + tid] = acc[r];
}

extern "C" void kernel_launch(void* const* d_in, const int* in_sizes, int n_in,
                              void* d_out, int out_size, void* d_ws, size_t ws_size,
                              hipStream_t stream) {
  const float* z0   = (const float*)d_in[0];
  const float* tdyn = (const float*)d_in[1];
  const float* Y    = (const float*)d_in[2];
  const float* Mm   = (const float*)d_in[3];
  const float* Hh   = (const float*)d_in[4];
  const int*   lens = (const int*)d_in[5];
  const float* W0   = (const float*)d_in[6];
  const float* b0   = (const float*)d_in[7];
  const float* W1   = (const float*)d_in[8];
  const float* b1   = (const float*)d_in[9];
  const float* W2   = (const float*)d_in[10];
  const float* b2   = (const float*)d_in[11];
  const float* Wih  = (const float*)d_in[12];
  const float* bih  = (const float*)d_in[13];
  const float* Whh  = (const float*)d_in[14];
  const float* bhh  = (const float*)d_in[15];
  float* out = (float*)d_out;

  const size_t gi_bytes = (size_t)B_ * T_ * GCOLS * sizeof(float);
  const int use_gi = (ws_size >= gi_bytes) ? 1 : 0;
  float* gi = (float*)d_ws;

  if (use_gi)
    gi_precompute<<<(B_ * T_) / 16, 384, 0, stream>>>(Y, Mm, Hh, Wih, bih, gi);

  odernn_kernel<<<B_, THR, 0, stream>>>(
      z0, tdyn, Y, Mm, Hh, lens, W0, b0, W1, b1, W2, b2,
      Wih, bih, Whh, bhh, use_gi ? gi : nullptr, out, use_gi);
}